// Round 1
// baseline (4428.870 us; speedup 1.0000x reference)
//
#include <hip/hip_runtime.h>
#include <math.h>

// Problem constants
#define N_ROWS 32768
#define K_CODES 8192
#define DIM 512

// Output layout (floats): quantized_st[N,D], probs[N,K], loss, perplexity
#define OUT_Q 0
#define OUT_P ((size_t)N_ROWS * DIM)                       // 16777216
#define OUT_LOSS (OUT_P + (size_t)N_ROWS * K_CODES)        // 285212672
#define OUT_PERP (OUT_LOSS + 1)

// Workspace layout (floats)
#define WS_XSQ 0
#define WS_WSQ (N_ROWS)                 // 32768
#define WS_LOSS (N_ROWS + K_CODES)      // 40960
#define WS_CNT (WS_LOSS + 1)            // 40961 .. 40961+8191

// ---------------------------------------------------------------------------
// Kernel 0: row squared norms for X (32768 rows) and W (8192 rows).
// One wave (64 threads) per row; DIM=512 => 8 floats/lane.
// ---------------------------------------------------------------------------
__global__ void sq_norms_kernel(const float* __restrict__ X,
                                const float* __restrict__ W,
                                float* __restrict__ ws) {
    int row = blockIdx.x;
    int lane = threadIdx.x;  // 0..63
    const float* src;
    float* dst;
    if (row < N_ROWS) {
        src = X + (size_t)row * DIM;
        dst = ws + WS_XSQ + row;
    } else {
        src = W + (size_t)(row - N_ROWS) * DIM;
        dst = ws + WS_WSQ + (row - N_ROWS);
    }
    float4 v0 = *(const float4*)(src + lane * 8);
    float4 v1 = *(const float4*)(src + lane * 8 + 4);
    float s = v0.x * v0.x + v0.y * v0.y + v0.z * v0.z + v0.w * v0.w
            + v1.x * v1.x + v1.y * v1.y + v1.z * v1.z + v1.w * v1.w;
#pragma unroll
    for (int off = 32; off > 0; off >>= 1) s += __shfl_down(s, off, 64);
    if (lane == 0) *dst = s;
}

// ---------------------------------------------------------------------------
// Kernel 1: fp32 SGEMM computing D[n,k] = xsq[n] + wsq[k] - 2 * (x_n . w_k),
// written into the probs region of d_out. 128x128 tile, BK=16, 8x8 microtile.
// ---------------------------------------------------------------------------
#define BM 128
#define BN 128
#define BK 16

__global__ void __launch_bounds__(256) gemm_dist_kernel(
    const float* __restrict__ X, const float* __restrict__ W,
    const float* __restrict__ ws, float* __restrict__ out) {
    __shared__ float As[BK][BM];  // As[k][m]
    __shared__ float Bs[BK][BN];  // Bs[k][n]

    const int bn = blockIdx.x * BN;  // code tile
    const int bm = blockIdx.y * BM;  // input-row tile
    const int tid = threadIdx.x;     // 0..255
    const int tx = tid & 15;         // 0..15
    const int ty = tid >> 4;         // 0..15

    // staging indices: 128 rows x 16 d per tile; thread loads 8 consecutive d
    const int lr = tid >> 1;         // 0..127 tile row
    const int lc = (tid & 1) * 8;    // 0 or 8

    float acc[8][8];
#pragma unroll
    for (int i = 0; i < 8; ++i)
#pragma unroll
        for (int j = 0; j < 8; ++j) acc[i][j] = 0.f;

    const float* aptr = X + (size_t)(bm + lr) * DIM + lc;
    const float* bptr = W + (size_t)(bn + lr) * DIM + lc;

    for (int k0 = 0; k0 < DIM; k0 += BK) {
        float4 a0 = *(const float4*)(aptr + k0);
        float4 a1 = *(const float4*)(aptr + k0 + 4);
        float4 b0 = *(const float4*)(bptr + k0);
        float4 b1 = *(const float4*)(bptr + k0 + 4);
        __syncthreads();  // previous iteration's LDS reads complete
        As[lc + 0][lr] = a0.x; As[lc + 1][lr] = a0.y;
        As[lc + 2][lr] = a0.z; As[lc + 3][lr] = a0.w;
        As[lc + 4][lr] = a1.x; As[lc + 5][lr] = a1.y;
        As[lc + 6][lr] = a1.z; As[lc + 7][lr] = a1.w;
        Bs[lc + 0][lr] = b0.x; Bs[lc + 1][lr] = b0.y;
        Bs[lc + 2][lr] = b0.z; Bs[lc + 3][lr] = b0.w;
        Bs[lc + 4][lr] = b1.x; Bs[lc + 5][lr] = b1.y;
        Bs[lc + 6][lr] = b1.z; Bs[lc + 7][lr] = b1.w;
        __syncthreads();
#pragma unroll
        for (int kk = 0; kk < BK; ++kk) {
            float a[8], b[8];
            *(float4*)&a[0] = *(const float4*)&As[kk][ty * 8];
            *(float4*)&a[4] = *(const float4*)&As[kk][ty * 8 + 4];
            *(float4*)&b[0] = *(const float4*)&Bs[kk][tx * 8];
            *(float4*)&b[4] = *(const float4*)&Bs[kk][tx * 8 + 4];
#pragma unroll
            for (int i = 0; i < 8; ++i)
#pragma unroll
                for (int j = 0; j < 8; ++j)
                    acc[i][j] = fmaf(a[i], b[j], acc[i][j]);
        }
    }

    // Epilogue: D = xsq[m] + wsq[n] - 2*dot
    const float* xsq = ws + WS_XSQ;
    const float* wsq = ws + WS_WSQ;
    const int m0 = bm + ty * 8;
    const int n0 = bn + tx * 8;
    float wn[8];
    *(float4*)&wn[0] = *(const float4*)(wsq + n0);
    *(float4*)&wn[4] = *(const float4*)(wsq + n0 + 4);
    float* Dout = out + OUT_P;
#pragma unroll
    for (int i = 0; i < 8; ++i) {
        float xv = xsq[m0 + i];
        float4 o0, o1;
        o0.x = xv + wn[0] - 2.f * acc[i][0];
        o0.y = xv + wn[1] - 2.f * acc[i][1];
        o0.z = xv + wn[2] - 2.f * acc[i][2];
        o0.w = xv + wn[3] - 2.f * acc[i][3];
        o1.x = xv + wn[4] - 2.f * acc[i][4];
        o1.y = xv + wn[5] - 2.f * acc[i][5];
        o1.z = xv + wn[6] - 2.f * acc[i][6];
        o1.w = xv + wn[7] - 2.f * acc[i][7];
        float* drow = Dout + (size_t)(m0 + i) * K_CODES + n0;
        *(float4*)(drow) = o0;
        *(float4*)(drow + 4) = o1;
    }
}

// ---------------------------------------------------------------------------
// Kernel 2: per-row (one block per input row): min/argmin, softmax in place,
// quantized gather + straight-through output, loss partial, counts histogram.
// ---------------------------------------------------------------------------
__global__ void __launch_bounds__(256) row_softmax_kernel(
    const float* __restrict__ X, const float* __restrict__ W,
    float* __restrict__ out, float* __restrict__ ws) {
    const int n = blockIdx.x;
    const int tid = threadIdx.x;  // 0..255
    __shared__ float sD[K_CODES];  // 32 KB
    __shared__ float red_v[256];
    __shared__ int red_i[256];

    float* Drow = out + OUT_P + (size_t)n * K_CODES;

    // Stage row into LDS (float4)
    float4* sD4 = (float4*)sD;
    for (int i = tid; i < K_CODES / 4; i += 256) {
        sD4[i] = *(const float4*)(Drow + i * 4);
    }
    __syncthreads();

    // min + argmin (numpy semantics: first index on ties)
    float bv = INFINITY;
    int bi = 0x7fffffff;
    for (int j = tid; j < K_CODES; j += 256) {
        float v = sD[j];
        if (v < bv || (v == bv && j < bi)) { bv = v; bi = j; }
    }
    red_v[tid] = bv;
    red_i[tid] = bi;
    __syncthreads();
    for (int s = 128; s > 0; s >>= 1) {
        if (tid < s) {
            float ov = red_v[tid + s];
            int oi = red_i[tid + s];
            if (ov < red_v[tid] || (ov == red_v[tid] && oi < red_i[tid])) {
                red_v[tid] = ov;
                red_i[tid] = oi;
            }
        }
        __syncthreads();
    }
    const float dmin = red_v[0];
    const int amin = red_i[0];
    __syncthreads();  // everyone has read red_v[0]/red_i[0]; safe to reuse

    // exp(dmin - d), overwrite sD, accumulate sum
    float s = 0.f;
    for (int j = tid; j < K_CODES; j += 256) {
        float e = __expf(dmin - sD[j]);
        sD[j] = e;
        s += e;
    }
    red_v[tid] = s;
    __syncthreads();
    for (int st = 128; st > 0; st >>= 1) {
        if (tid < st) red_v[tid] += red_v[tid + st];
        __syncthreads();
    }
    const float inv = 1.0f / red_v[0];
    __syncthreads();

    // write probs in place
    for (int i = tid; i < K_CODES / 4; i += 256) {
        float4 e = sD4[i];
        float4 p;
        p.x = e.x * inv; p.y = e.y * inv; p.z = e.z * inv; p.w = e.w * inv;
        *(float4*)(Drow + i * 4) = p;
    }

    // quantized gather + straight-through output + loss partial
    const float* wrow = W + (size_t)amin * DIM;
    const float* xrow = X + (size_t)n * DIM;
    float* qrow = out + OUT_Q + (size_t)n * DIM;
    float errs = 0.f;
    for (int c = tid; c < DIM; c += 256) {
        float x = xrow[c];
        float q = wrow[c];
        float d = q - x;
        qrow[c] = x + d;  // same op order as reference straight-through
        errs += d * d;
    }
    red_v[tid] = errs;
    __syncthreads();
    for (int st = 128; st > 0; st >>= 1) {
        if (tid < st) red_v[tid] += red_v[tid + st];
        __syncthreads();
    }
    if (tid == 0) {
        atomicAdd(ws + WS_LOSS, red_v[0]);
        atomicAdd(ws + WS_CNT + amin, 1.0f);
    }
}

// ---------------------------------------------------------------------------
// Kernel 3: finalize loss + perplexity
// ---------------------------------------------------------------------------
__global__ void __launch_bounds__(256) finalize_kernel(
    float* __restrict__ out, const float* __restrict__ ws) {
    __shared__ float red[256];
    const int tid = threadIdx.x;
    float ent = 0.f;
    for (int j = tid; j < K_CODES; j += 256) {
        float p = ws[WS_CNT + j] * (1.0f / (float)N_ROWS);
        ent -= p * logf(p + 1e-10f);
    }
    red[tid] = ent;
    __syncthreads();
    for (int st = 128; st > 0; st >>= 1) {
        if (tid < st) red[tid] += red[tid + st];
        __syncthreads();
    }
    if (tid == 0) {
        float mse = ws[WS_LOSS] * (1.0f / ((float)N_ROWS * (float)DIM));
        out[OUT_LOSS] = mse + 0.25f * mse;  // q_latent + commitment * e_latent
        out[OUT_PERP] = expf(red[0]);
    }
}

// ---------------------------------------------------------------------------
extern "C" void kernel_launch(void* const* d_in, const int* in_sizes, int n_in,
                              void* d_out, int out_size, void* d_ws, size_t ws_size,
                              hipStream_t stream) {
    const float* X = (const float*)d_in[0];  // [32768, 512]
    const float* W = (const float*)d_in[1];  // [8192, 512]
    float* out = (float*)d_out;
    float* ws = (float*)d_ws;

    // zero loss accumulator + counts histogram (ws is poisoned 0xAA)
    hipMemsetAsync(ws + WS_LOSS, 0, (1 + K_CODES) * sizeof(float), stream);

    sq_norms_kernel<<<N_ROWS + K_CODES, 64, 0, stream>>>(X, W, ws);

    dim3 ggrid(K_CODES / BN, N_ROWS / BM);  // (64, 256)
    gemm_dist_kernel<<<ggrid, 256, 0, stream>>>(X, W, ws, out);

    row_softmax_kernel<<<N_ROWS, 256, 0, stream>>>(X, W, out, ws);

    finalize_kernel<<<1, 256, 0, stream>>>(out, ws);
}

// Round 2
// 2443.960 us; speedup vs baseline: 1.8122x; 1.8122x over previous
//
#include <hip/hip_runtime.h>
#include <hip/hip_fp16.h>
#include <math.h>

// Problem constants
#define N_ROWS 32768
#define K_CODES 8192
#define DIM 512

// Output layout (floats): quantized_st[N,D], probs[N,K], loss, perplexity
#define OUT_Q 0
#define OUT_P ((size_t)N_ROWS * DIM)                       // 16777216
#define OUT_LOSS (OUT_P + (size_t)N_ROWS * K_CODES)        // 285212672
#define OUT_PERP (OUT_LOSS + 1)

// Workspace layout (floats)
#define WS_XSQ 0
#define WS_WSQ (N_ROWS)                 // 32768
#define WS_LOSS (N_ROWS + K_CODES)      // 40960
#define WS_CNT (WS_LOSS + 1)            // 40961 .. 40961+8191
#define WS_F16 51200                    // float offset where f16 region begins

// f16 region layout (in _Float16 elements, relative to f16 base)
#define XH_OFF ((size_t)0)
#define XL_OFF ((size_t)N_ROWS * DIM)
#define WH_OFF ((size_t)2 * N_ROWS * DIM)
#define WL_OFF ((size_t)2 * N_ROWS * DIM + (size_t)K_CODES * DIM)
#define F16_COUNT ((size_t)2 * (N_ROWS + K_CODES) * DIM)   // 41943040 halves
#define WS_NEEDED ((size_t)WS_F16 * 4 + F16_COUNT * 2)     // ~84.1 MB

typedef _Float16 f16x8 __attribute__((ext_vector_type(8)));
typedef float f32x4 __attribute__((ext_vector_type(4)));

__device__ inline void load_lds16(const void* g, void* l) {
    __builtin_amdgcn_global_load_lds((const __attribute__((address_space(1))) void*)g,
                                     (__attribute__((address_space(3))) void*)l,
                                     16, 0, 0);
}

// ---------------------------------------------------------------------------
// Kernel 0: row squared norms for X (32768 rows) and W (8192 rows).
// ---------------------------------------------------------------------------
__global__ void sq_norms_kernel(const float* __restrict__ X,
                                const float* __restrict__ W,
                                float* __restrict__ ws) {
    int row = blockIdx.x;
    int lane = threadIdx.x;  // 0..63
    const float* src;
    float* dst;
    if (row < N_ROWS) {
        src = X + (size_t)row * DIM;
        dst = ws + WS_XSQ + row;
    } else {
        src = W + (size_t)(row - N_ROWS) * DIM;
        dst = ws + WS_WSQ + (row - N_ROWS);
    }
    float4 v0 = *(const float4*)(src + lane * 8);
    float4 v1 = *(const float4*)(src + lane * 8 + 4);
    float s = v0.x * v0.x + v0.y * v0.y + v0.z * v0.z + v0.w * v0.w
            + v1.x * v1.x + v1.y * v1.y + v1.z * v1.z + v1.w * v1.w;
#pragma unroll
    for (int off = 32; off > 0; off >>= 1) s += __shfl_down(s, off, 64);
    if (lane == 0) *dst = s;
}

// ---------------------------------------------------------------------------
// Kernel 0b: split X and W into fp16 hi/lo pairs (exact 3-term decomposition).
// Each thread handles 8 consecutive floats.
// ---------------------------------------------------------------------------
__global__ void __launch_bounds__(256) convert_split_kernel(
    const float* __restrict__ X, const float* __restrict__ W,
    _Float16* __restrict__ f16base) {
    const size_t NX8 = (size_t)N_ROWS * DIM / 8;  // 2097152
    size_t t = (size_t)blockIdx.x * 256 + threadIdx.x;
    const float* src;
    _Float16 *hd, *ld;
    if (t < NX8) {
        src = X + t * 8;
        hd = f16base + XH_OFF + t * 8;
        ld = f16base + XL_OFF + t * 8;
    } else {
        size_t u = t - NX8;
        src = W + u * 8;
        hd = f16base + WH_OFF + u * 8;
        ld = f16base + WL_OFF + u * 8;
    }
    float4 v0 = *(const float4*)src;
    float4 v1 = *(const float4*)(src + 4);
    float v[8] = {v0.x, v0.y, v0.z, v0.w, v1.x, v1.y, v1.z, v1.w};
    f16x8 h, l;
#pragma unroll
    for (int i = 0; i < 8; ++i) {
        _Float16 hv = (_Float16)v[i];
        h[i] = hv;
        l[i] = (_Float16)(v[i] - (float)hv);
    }
    *(f16x8*)hd = h;
    *(f16x8*)ld = l;
}

// ---------------------------------------------------------------------------
// Kernel 1 (MFMA): D[m,n] = xsq[m] + wsq[n] - 2 * (x_m . w_n) via fp16 3-term
// split GEMM: dot = Xh.Wh + Xh.Wl + Xl.Wh (lo*lo dropped, ~2^-22 relative).
// 128x128 tile, BK=32, 4 waves each computing 64x64 via 4x4 16x16x32 frags.
// Staging via global_load_lds(16B); LDS rows 32 halves (64B) with XOR chunk
// swizzle (pos = chunk ^ ((row>>1)&3)) -> 2-way-max bank aliasing (free).
// ---------------------------------------------------------------------------
__global__ void __launch_bounds__(256) gemm_dist_mfma_kernel(
    const _Float16* __restrict__ f16base, const float* __restrict__ ws,
    float* __restrict__ out) {
    __shared__ _Float16 lds[4][128][32];  // Ah, Al, Bh, Bl : 32 KB

    const int tid = threadIdx.x;
    const int w = tid >> 6;    // wave 0..3
    const int lane = tid & 63;
    const int bn = blockIdx.x * 128;  // code tile base
    const int bm = blockIdx.y * 128;  // input-row tile base
    const int wr = w >> 1;            // wave m-quadrant (0..1)
    const int wc = w & 1;             // wave n-quadrant (0..1)

    // Staging: wave w stages buffer w (0=Xh,1=Xl,2=Wh,3=Wl)
    const _Float16* src_base;
    int tile_row_base;
    if (w == 0)      { src_base = f16base + XH_OFF; tile_row_base = bm; }
    else if (w == 1) { src_base = f16base + XL_OFF; tile_row_base = bm; }
    else if (w == 2) { src_base = f16base + WH_OFF; tile_row_base = bn; }
    else             { src_base = f16base + WL_OFF; tile_row_base = bn; }

    const int lrow = lane >> 2;  // row within 16-row group
    const int p = lane & 3;      // chunk position 0..3 (8 halves each)

    f32x4 acc[4][4];
#pragma unroll
    for (int i = 0; i < 4; ++i)
#pragma unroll
        for (int j = 0; j < 4; ++j) acc[i][j] = (f32x4){0.f, 0.f, 0.f, 0.f};

    const int q = lane >> 4;    // frag k-chunk 0..3
    const int fm = lane & 15;   // frag row/col within 16

    for (int k0 = 0; k0 < DIM; k0 += 32) {
        __syncthreads();  // WAR: previous iteration's frag reads done
#pragma unroll
        for (int e = 0; e < 8; ++e) {
            int m = e * 16 + lrow;
            int c = p ^ ((m >> 1) & 3);  // global chunk stored at position p
            const _Float16* gp =
                src_base + (size_t)(tile_row_base + m) * DIM + k0 + c * 8;
            load_lds16(gp, &lds[w][e * 16][0]);
        }
        __syncthreads();  // RAW: vmcnt drain + barrier

        f16x8 ah[4], al[4], bh[4], bl[4];
#pragma unroll
        for (int i = 0; i < 4; ++i) {
            int am = wr * 64 + i * 16 + fm;
            int sa = (am >> 1) & 3;
            ah[i] = *(const f16x8*)&lds[0][am][(q ^ sa) * 8];
            al[i] = *(const f16x8*)&lds[1][am][(q ^ sa) * 8];
            int bb = wc * 64 + i * 16 + fm;
            int sb = (bb >> 1) & 3;
            bh[i] = *(const f16x8*)&lds[2][bb][(q ^ sb) * 8];
            bl[i] = *(const f16x8*)&lds[3][bb][(q ^ sb) * 8];
        }
#pragma unroll
        for (int i = 0; i < 4; ++i)
#pragma unroll
            for (int j = 0; j < 4; ++j) {
                acc[i][j] = __builtin_amdgcn_mfma_f32_16x16x32_f16(
                    ah[i], bh[j], acc[i][j], 0, 0, 0);
                acc[i][j] = __builtin_amdgcn_mfma_f32_16x16x32_f16(
                    ah[i], bl[j], acc[i][j], 0, 0, 0);
                acc[i][j] = __builtin_amdgcn_mfma_f32_16x16x32_f16(
                    al[i], bh[j], acc[i][j], 0, 0, 0);
            }
    }

    // Epilogue: D = xsq[m] + wsq[n] - 2*dot
    // C/D layout: col = lane&15, row = (lane>>4)*4 + r  (m89-verified)
    const float* xsq = ws + WS_XSQ;
    const float* wsq = ws + WS_WSQ;
    float* Dout = out + OUT_P;
    const int q4 = (lane >> 4) * 4;
#pragma unroll
    for (int i = 0; i < 4; ++i) {
#pragma unroll
        for (int j = 0; j < 4; ++j) {
            int n = bn + wc * 64 + j * 16 + fm;
            float wn = wsq[n];
#pragma unroll
            for (int r = 0; r < 4; ++r) {
                int m = bm + wr * 64 + i * 16 + q4 + r;
                Dout[(size_t)m * K_CODES + n] = xsq[m] + wn - 2.f * acc[i][j][r];
            }
        }
    }
}

// ---------------------------------------------------------------------------
// Kernel 1 fallback (fp32 VALU SGEMM) — used only if ws is too small for the
// f16 split buffers. Identical to round-1 kernel.
// ---------------------------------------------------------------------------
#define BM 128
#define BN 128
#define BK 16

__global__ void __launch_bounds__(256) gemm_dist_fp32_kernel(
    const float* __restrict__ X, const float* __restrict__ W,
    const float* __restrict__ ws, float* __restrict__ out) {
    __shared__ float As[BK][BM];
    __shared__ float Bs[BK][BN];

    const int bn = blockIdx.x * BN;
    const int bm = blockIdx.y * BM;
    const int tid = threadIdx.x;
    const int tx = tid & 15;
    const int ty = tid >> 4;
    const int lr = tid >> 1;
    const int lc = (tid & 1) * 8;

    float acc[8][8];
#pragma unroll
    for (int i = 0; i < 8; ++i)
#pragma unroll
        for (int j = 0; j < 8; ++j) acc[i][j] = 0.f;

    const float* aptr = X + (size_t)(bm + lr) * DIM + lc;
    const float* bptr = W + (size_t)(bn + lr) * DIM + lc;

    for (int k0 = 0; k0 < DIM; k0 += BK) {
        float4 a0 = *(const float4*)(aptr + k0);
        float4 a1 = *(const float4*)(aptr + k0 + 4);
        float4 b0 = *(const float4*)(bptr + k0);
        float4 b1 = *(const float4*)(bptr + k0 + 4);
        __syncthreads();
        As[lc + 0][lr] = a0.x; As[lc + 1][lr] = a0.y;
        As[lc + 2][lr] = a0.z; As[lc + 3][lr] = a0.w;
        As[lc + 4][lr] = a1.x; As[lc + 5][lr] = a1.y;
        As[lc + 6][lr] = a1.z; As[lc + 7][lr] = a1.w;
        Bs[lc + 0][lr] = b0.x; Bs[lc + 1][lr] = b0.y;
        Bs[lc + 2][lr] = b0.z; Bs[lc + 3][lr] = b0.w;
        Bs[lc + 4][lr] = b1.x; Bs[lc + 5][lr] = b1.y;
        Bs[lc + 6][lr] = b1.z; Bs[lc + 7][lr] = b1.w;
        __syncthreads();
#pragma unroll
        for (int kk = 0; kk < BK; ++kk) {
            float a[8], b[8];
            *(float4*)&a[0] = *(const float4*)&As[kk][ty * 8];
            *(float4*)&a[4] = *(const float4*)&As[kk][ty * 8 + 4];
            *(float4*)&b[0] = *(const float4*)&Bs[kk][tx * 8];
            *(float4*)&b[4] = *(const float4*)&Bs[kk][tx * 8 + 4];
#pragma unroll
            for (int i = 0; i < 8; ++i)
#pragma unroll
                for (int j = 0; j < 8; ++j)
                    acc[i][j] = fmaf(a[i], b[j], acc[i][j]);
        }
    }

    const float* xsq = ws + WS_XSQ;
    const float* wsq = ws + WS_WSQ;
    const int m0 = bm + ty * 8;
    const int n0 = bn + tx * 8;
    float wn[8];
    *(float4*)&wn[0] = *(const float4*)(wsq + n0);
    *(float4*)&wn[4] = *(const float4*)(wsq + n0 + 4);
    float* Dout = out + OUT_P;
#pragma unroll
    for (int i = 0; i < 8; ++i) {
        float xv = xsq[m0 + i];
        float4 o0, o1;
        o0.x = xv + wn[0] - 2.f * acc[i][0];
        o0.y = xv + wn[1] - 2.f * acc[i][1];
        o0.z = xv + wn[2] - 2.f * acc[i][2];
        o0.w = xv + wn[3] - 2.f * acc[i][3];
        o1.x = xv + wn[4] - 2.f * acc[i][4];
        o1.y = xv + wn[5] - 2.f * acc[i][5];
        o1.z = xv + wn[6] - 2.f * acc[i][6];
        o1.w = xv + wn[7] - 2.f * acc[i][7];
        float* drow = Dout + (size_t)(m0 + i) * K_CODES + n0;
        *(float4*)(drow) = o0;
        *(float4*)(drow + 4) = o1;
    }
}

// ---------------------------------------------------------------------------
// Kernel 2: per-row: min/argmin, softmax in place, quantized gather +
// straight-through output, loss partial, counts histogram.
// ---------------------------------------------------------------------------
__global__ void __launch_bounds__(256) row_softmax_kernel(
    const float* __restrict__ X, const float* __restrict__ W,
    float* __restrict__ out, float* __restrict__ ws) {
    const int n = blockIdx.x;
    const int tid = threadIdx.x;
    __shared__ float sD[K_CODES];  // 32 KB
    __shared__ float red_v[256];
    __shared__ int red_i[256];

    float* Drow = out + OUT_P + (size_t)n * K_CODES;

    float4* sD4 = (float4*)sD;
    for (int i = tid; i < K_CODES / 4; i += 256) {
        sD4[i] = *(const float4*)(Drow + i * 4);
    }
    __syncthreads();

    float bv = INFINITY;
    int bi = 0x7fffffff;
    for (int j = tid; j < K_CODES; j += 256) {
        float v = sD[j];
        if (v < bv || (v == bv && j < bi)) { bv = v; bi = j; }
    }
    red_v[tid] = bv;
    red_i[tid] = bi;
    __syncthreads();
    for (int s = 128; s > 0; s >>= 1) {
        if (tid < s) {
            float ov = red_v[tid + s];
            int oi = red_i[tid + s];
            if (ov < red_v[tid] || (ov == red_v[tid] && oi < red_i[tid])) {
                red_v[tid] = ov;
                red_i[tid] = oi;
            }
        }
        __syncthreads();
    }
    const float dmin = red_v[0];
    const int amin = red_i[0];
    __syncthreads();

    float s = 0.f;
    for (int j = tid; j < K_CODES; j += 256) {
        float e = __expf(dmin - sD[j]);
        sD[j] = e;
        s += e;
    }
    red_v[tid] = s;
    __syncthreads();
    for (int st = 128; st > 0; st >>= 1) {
        if (tid < st) red_v[tid] += red_v[tid + st];
        __syncthreads();
    }
    const float inv = 1.0f / red_v[0];
    __syncthreads();

    for (int i = tid; i < K_CODES / 4; i += 256) {
        float4 e = sD4[i];
        float4 p;
        p.x = e.x * inv; p.y = e.y * inv; p.z = e.z * inv; p.w = e.w * inv;
        *(float4*)(Drow + i * 4) = p;
    }

    const float* wrow = W + (size_t)amin * DIM;
    const float* xrow = X + (size_t)n * DIM;
    float* qrow = out + OUT_Q + (size_t)n * DIM;
    float errs = 0.f;
    for (int c = tid; c < DIM; c += 256) {
        float x = xrow[c];
        float qv = wrow[c];
        float d = qv - x;
        qrow[c] = x + d;
        errs += d * d;
    }
    red_v[tid] = errs;
    __syncthreads();
    for (int st = 128; st > 0; st >>= 1) {
        if (tid < st) red_v[tid] += red_v[tid + st];
        __syncthreads();
    }
    if (tid == 0) {
        atomicAdd(ws + WS_LOSS, red_v[0]);
        atomicAdd(ws + WS_CNT + amin, 1.0f);
    }
}

// ---------------------------------------------------------------------------
// Kernel 3: finalize loss + perplexity
// ---------------------------------------------------------------------------
__global__ void __launch_bounds__(256) finalize_kernel(
    float* __restrict__ out, const float* __restrict__ ws) {
    __shared__ float red[256];
    const int tid = threadIdx.x;
    float ent = 0.f;
    for (int j = tid; j < K_CODES; j += 256) {
        float p = ws[WS_CNT + j] * (1.0f / (float)N_ROWS);
        ent -= p * logf(p + 1e-10f);
    }
    red[tid] = ent;
    __syncthreads();
    for (int st = 128; st > 0; st >>= 1) {
        if (tid < st) red[tid] += red[tid + st];
        __syncthreads();
    }
    if (tid == 0) {
        float mse = ws[WS_LOSS] * (1.0f / ((float)N_ROWS * (float)DIM));
        out[OUT_LOSS] = mse + 0.25f * mse;
        out[OUT_PERP] = expf(red[0]);
    }
}

// ---------------------------------------------------------------------------
extern "C" void kernel_launch(void* const* d_in, const int* in_sizes, int n_in,
                              void* d_out, int out_size, void* d_ws, size_t ws_size,
                              hipStream_t stream) {
    const float* X = (const float*)d_in[0];  // [32768, 512]
    const float* W = (const float*)d_in[1];  // [8192, 512]
    float* out = (float*)d_out;
    float* ws = (float*)d_ws;

    hipMemsetAsync(ws + WS_LOSS, 0, (1 + K_CODES) * sizeof(float), stream);

    sq_norms_kernel<<<N_ROWS + K_CODES, 64, 0, stream>>>(X, W, ws);

    if (ws_size >= WS_NEEDED) {
        _Float16* f16base = (_Float16*)(ws + WS_F16);
        // split conversion: (16.8M + 4.2M) / 8 elements per thread / 256
        const int conv_blocks = (int)(((size_t)(N_ROWS + K_CODES) * DIM / 8 + 255) / 256);
        convert_split_kernel<<<conv_blocks, 256, 0, stream>>>(X, W, f16base);

        dim3 ggrid(K_CODES / 128, N_ROWS / 128);  // (64, 256)
        gemm_dist_mfma_kernel<<<ggrid, 256, 0, stream>>>(f16base, ws, out);
    } else {
        dim3 ggrid(K_CODES / BN, N_ROWS / BM);
        gemm_dist_fp32_kernel<<<ggrid, 256, 0, stream>>>(X, W, ws, out);
    }

    row_softmax_kernel<<<N_ROWS, 256, 0, stream>>>(X, W, out, ws);

    finalize_kernel<<<1, 256, 0, stream>>>(out, ws);
}